// Round 13
// baseline (183.028 us; speedup 1.0000x reference)
//
#include <hip/hip_runtime.h>
#include <math.h>

#define BB 8
#define PP 2048
#define VV 2562
#define NV 8192
#define FF 16384
#define EPSF 1e-12f
#define NSLICE 8
#define FSLICE (FF / NSLICE)   // 2048 faces per block
#define TS 512                 // refs per LDS tile in nn_loss

// ---------------------------------------------------------------------------
// Kernel 1: per-face normals -> per-(batch,slice) PARTIAL normal buffers.
// 64 blocks = 8 batches x 8 face-slices, 1024 threads, private 98KB LDS
// accumulator. Round-7 lesson: scatter phase scales ~linearly with block
// count (190us@8 -> ~48us@32), and the contiguous atomicAdd merge was ~25MB
// of RMW at the coherence point. So: more blocks (64) and NO atomic merge --
// each block writes its partial with plain coalesced stores; nn_loss sums
// the 8 partials at its (few) gather points. No nrm memset needed either.
// ---------------------------------------------------------------------------
__global__ __launch_bounds__(1024) void face_normals_kernel(
    const float* __restrict__ gtv,   // (B, NV, 3)
    const int*   __restrict__ faces, // (B, FF, 3) int32
    float*       __restrict__ part)  // (B, NSLICE, NV*3) partials
{
    __shared__ float acc[NV * 3];    // 98304 B
    const int b = blockIdx.x >> 3;   // batch
    const int s = blockIdx.x & 7;    // face slice

    for (int i = threadIdx.x; i < NV * 3; i += 1024) acc[i] = 0.f;
    __syncthreads();

    const int*   fb = faces + ((size_t)b * FF + (size_t)s * FSLICE) * 3;
    const float* vb = gtv   + (size_t)b * NV * 3;

    for (int f = threadIdx.x; f < FSLICE; f += 1024) {
        int i0 = fb[f*3+0], i1 = fb[f*3+1], i2 = fb[f*3+2];

        float v0x = vb[i0*3+0], v0y = vb[i0*3+1], v0z = vb[i0*3+2];
        float v1x = vb[i1*3+0], v1y = vb[i1*3+1], v1z = vb[i1*3+2];
        float v2x = vb[i2*3+0], v2y = vb[i2*3+1], v2z = vb[i2*3+2];

        float e1x = v1x - v0x, e1y = v1y - v0y, e1z = v1z - v0z;
        float e2x = v2x - v0x, e2y = v2y - v0y, e2z = v2z - v0z;

        float fnx = e1y * e2z - e1z * e2y;
        float fny = e1z * e2x - e1x * e2z;
        float fnz = e1x * e2y - e1y * e2x;

        atomicAdd(&acc[i0*3+0], fnx); atomicAdd(&acc[i0*3+1], fny); atomicAdd(&acc[i0*3+2], fnz);
        atomicAdd(&acc[i1*3+0], fnx); atomicAdd(&acc[i1*3+1], fny); atomicAdd(&acc[i1*3+2], fnz);
        atomicAdd(&acc[i2*3+0], fnx); atomicAdd(&acc[i2*3+1], fny); atomicAdd(&acc[i2*3+2], fnz);
    }
    __syncthreads();

    // Plain coalesced store of the private partial (no atomics, no RMW).
    float* pb = part + ((size_t)b * NSLICE + s) * (NV * 3);
    for (int i = threadIdx.x; i < NV * 3; i += 1024) pb[i] = acc[i];
}

// ---------------------------------------------------------------------------
// Kernel 2: NN + loss with LDS-staged ref tiles. Block = 4 waves = 16 points
// (4 pts/wave). Refs staged in 512-ref double-buffered LDS tiles shared by
// all 4 waves (4x less global ref traffic; round-7 showed 55% VALUBusy =
// latency-stalled on the 3 dependent gathers/iter). Next tile is loaded to
// registers BEFORE scanning the current tile (issue-early/write-late), so
// HBM/L2 latency hides under the scan VALU. Score = rr - 2 q.r (|q|^2 is
// argmin-invariant). Butterfly shfl argmin, lowest-index tie-break. Lane 0
// sums the NSLICE normal partials at its 4 gather points; one atomicAdd per
// block into out.
// ---------------------------------------------------------------------------
__global__ __launch_bounds__(256) void nn_loss_kernel(
    const float* __restrict__ pp,   // (B, P, 3)  pred_points
    const float* __restrict__ pv,   // (B, V, 3)  pred_vertices
    const float* __restrict__ gtv,  // (B, NV, 3) gt_vertices
    const float* __restrict__ part, // (B, NSLICE, NV*3) normal partials
    float*       __restrict__ out)  // scalar accumulator (pre-zeroed)
{
    __shared__ float tile[2][TS * 3];   // 12288 B double-buffered ref tile
    __shared__ float wsum[4];

    const int tid  = threadIdx.x;
    const int lane = tid & 63;
    const int wave = tid >> 6;                  // 0..3
    const int gw   = blockIdx.x * 4 + wave;     // global wave id 0..4095
    const int b    = gw >> 9;                   // 512 waves per batch
    const int p0   = (gw & 511) * 4;            // first of 4 points

    // Query points (wave-uniform loads, L1 broadcast); raw + doubled-neg.
    float px[4], py[4], pz[4], m2x[4], m2y[4], m2z[4];
    const float* ppb = pp + ((size_t)b * PP + p0) * 3;
#pragma unroll
    for (int j = 0; j < 4; ++j) {
        px[j] = ppb[j*3+0]; py[j] = ppb[j*3+1]; pz[j] = ppb[j*3+2];
        m2x[j] = -2.f * px[j]; m2y[j] = -2.f * py[j]; m2z[j] = -2.f * pz[j];
    }

    float bd[4]; int bi[4];

    // ================= gt_vertices scan: 16 tiles of 512, no tails ========
#pragma unroll
    for (int j = 0; j < 4; ++j) { bd[j] = INFINITY; bi[j] = 0; }
    {
        const float* gsrc = gtv + (size_t)b * NV * 3;   // 24576 floats
        // prologue: stage tile 0
#pragma unroll
        for (int k = 0; k < 6; ++k)
            tile[0][tid + k * 256] = gsrc[tid + k * 256];
        __syncthreads();

        for (int t = 0; t < NV / TS; ++t) {
            const int cur = t & 1, nxt = cur ^ 1;
            const bool have_next = (t + 1) < (NV / TS);
            float g[6];
            if (have_next) {
#pragma unroll
                for (int k = 0; k < 6; ++k)
                    g[k] = gsrc[(t + 1) * (TS * 3) + tid + k * 256];
            }
            // scan current tile: 8 iters x 64 lanes
#pragma unroll 2
            for (int i = 0; i < TS / 64; ++i) {
                int r = lane + i * 64;
                float rx = tile[cur][r*3+0];
                float ry = tile[cur][r*3+1];
                float rz = tile[cur][r*3+2];
                float rr = fmaf(rx, rx, fmaf(ry, ry, rz * rz));
                int rg = t * TS + r;
#pragma unroll
                for (int j = 0; j < 4; ++j) {
                    float sc = fmaf(m2x[j], rx, fmaf(m2y[j], ry, fmaf(m2z[j], rz, rr)));
                    bool take = sc < bd[j];      // strict <: lowest idx
                    bd[j] = take ? sc : bd[j];
                    bi[j] = take ? rg : bi[j];
                }
            }
            if (have_next) {
#pragma unroll
                for (int k = 0; k < 6; ++k)
                    tile[nxt][tid + k * 256] = g[k];
            }
            __syncthreads();
        }
    }
    int gt_idx[4];
#pragma unroll
    for (int j = 0; j < 4; ++j) {
        float d = bd[j]; int idx = bi[j];
#pragma unroll
        for (int off = 32; off; off >>= 1) {
            float od = __shfl_xor(d, off);
            int   oi = __shfl_xor(idx, off);
            if (od < d || (od == d && oi < idx)) { d = od; idx = oi; }
        }
        gt_idx[j] = idx;
    }

    // ================= pred_vertices scan: 6 tiles (5x512 + 2) ============
#pragma unroll
    for (int j = 0; j < 4; ++j) { bd[j] = INFINITY; bi[j] = 0; }
    {
        const float* psrc = pv + (size_t)b * VV * 3;    // 7686 floats
        const int NT = (VV + TS - 1) / TS;              // 6
        // prologue: stage tile 0 (full)
#pragma unroll
        for (int k = 0; k < 6; ++k)
            tile[0][tid + k * 256] = psrc[tid + k * 256];
        __syncthreads();

        for (int t = 0; t < NT; ++t) {
            const int cur = t & 1, nxt = cur ^ 1;
            const bool have_next = (t + 1) < NT;
            float g[6];
            if (have_next) {
#pragma unroll
                for (int k = 0; k < 6; ++k) {
                    int gi = (t + 1) * (TS * 3) + tid + k * 256;
                    g[k] = (gi < VV * 3) ? psrc[gi] : 0.f;
                }
            }
            const int nt = (VV - t * TS < TS) ? (VV - t * TS) : TS;
            for (int i = 0; i < (nt + 63) / 64; ++i) {
                int r = lane + i * 64;
                bool ok = r < nt;
                float rx = tile[cur][r*3+0];   // stale-but-finite when !ok
                float ry = tile[cur][r*3+1];
                float rz = tile[cur][r*3+2];
                float rr = fmaf(rx, rx, fmaf(ry, ry, rz * rz));
                int rg = t * TS + r;
#pragma unroll
                for (int j = 0; j < 4; ++j) {
                    float sc = fmaf(m2x[j], rx, fmaf(m2y[j], ry, fmaf(m2z[j], rz, rr)));
                    sc = ok ? sc : INFINITY;
                    bool take = sc < bd[j];
                    bd[j] = take ? sc : bd[j];
                    bi[j] = take ? rg : bi[j];
                }
            }
            if (have_next) {
#pragma unroll
                for (int k = 0; k < 6; ++k)
                    tile[nxt][tid + k * 256] = g[k];
            }
            __syncthreads();
        }
    }
    int pr_idx[4];
#pragma unroll
    for (int j = 0; j < 4; ++j) {
        float d = bd[j]; int idx = bi[j];
#pragma unroll
        for (int off = 32; off; off >>= 1) {
            float od = __shfl_xor(d, off);
            int   oi = __shfl_xor(idx, off);
            if (od < d || (od == d && oi < idx)) { d = od; idx = oi; }
        }
        pr_idx[j] = idx;
    }

    // ---- loss terms (lane 0 of each wave); sum NSLICE normal partials ----
    if (lane == 0) {
        const float* pvb = pv + (size_t)b * VV * 3;
        const float* pt0 = part + (size_t)b * NSLICE * (NV * 3);
        float s = 0.f;
#pragma unroll
        for (int j = 0; j < 4; ++j) {
            int vi = pr_idx[j];
            float ex = px[j] - pvb[vi*3+0];
            float ey = py[j] - pvb[vi*3+1];
            float ez = pz[j] - pvb[vi*3+2];
            float el = fmaxf(sqrtf(fmaf(ex, ex, fmaf(ey, ey, ez * ez))), EPSF);

            int ni = gt_idx[j];
            float nx = 0.f, ny = 0.f, nz = 0.f;
#pragma unroll
            for (int sl = 0; sl < NSLICE; ++sl) {
                const float* pb = pt0 + (size_t)sl * (NV * 3) + (size_t)ni * 3;
                nx += pb[0]; ny += pb[1]; nz += pb[2];
            }
            float nl = fmaxf(sqrtf(fmaf(nx, nx, fmaf(ny, ny, nz * nz))), EPSF);

            float dot = fmaf(ex, nx, fmaf(ey, ny, ez * nz));
            s += fabsf(dot) / (el * nl);
        }
        wsum[wave] = s;
    }
    __syncthreads();
    if (tid == 0)
        atomicAdd(out, (wsum[0] + wsum[1] + wsum[2] + wsum[3]) *
                       (1.f / (float)(BB * PP)));
}

// ---------------------------------------------------------------------------
extern "C" void kernel_launch(void* const* d_in, const int* in_sizes, int n_in,
                              void* d_out, int out_size, void* d_ws, size_t ws_size,
                              hipStream_t stream) {
    const float* pp    = (const float*)d_in[0];  // pred_points   (8,2048,3)
    const float* pv    = (const float*)d_in[1];  // pred_vertices (8,2562,3)
    const float* gtv   = (const float*)d_in[2];  // gt_vertices   (8,8192,3)
    const int*   faces = (const int*)d_in[3];    // gt_faces      (8,16384,3)
    float* out = (float*)d_out;

    float* part = (float*)d_ws;  // (B, NSLICE, NV*3) = 6291456 B partials
                                 // (fully written by face_normals, no memset)

    // Zero the scalar output (poisoned 0xAA before every timed launch).
    hipMemsetAsync(out, 0, sizeof(float), stream);

    face_normals_kernel<<<BB * NSLICE, 1024, 0, stream>>>(gtv, faces, part);

    nn_loss_kernel<<<(BB * PP) / 16, 256, 0, stream>>>(pp, pv, gtv, part, out);
}